// Round 9
// baseline (372.822 us; speedup 1.0000x reference)
//
#include <hip/hip_runtime.h>

// ---------------------------------------------------------------------------
// TransVLAD fused pipeline for MI355X (gfx950)
// Shapes: N=32, C=512, H=W=32 (P=1024), E=1024, G=8, D=128, K=64
// out: [N, K*D] fp32 (262144)
//
// R9: FUSION. xe/S/att had exactly one consumer (k4) and all coupling is
// per-(g, p-tile) local. kf computes [W1_g; V_g; W2W1_g](208xC) * xhat^T
// per (n, g, 128-px tile), then softmax+gate+agg entirely in LDS ->
// writes only agg partials. Deletes k2's 96MB write + k4's 97MB read +
// k3's xhat re-read (~190MB HBM round-trip). LDS rows padded to 144B
// (9 chunks) to kill k2's 1.9e7 16-way fragment-read bank conflicts.
// ws total ~102.9MB (was 137.4).
// ---------------------------------------------------------------------------

#define N_  32
#define C_  512
#define P_  1024
#define E_  1024
#define G_  8
#define D_  128
#define K_  64

#define AB2_GS (208 * 512)   // shorts per weight group

typedef __attribute__((ext_vector_type(8))) short bf16x8;
typedef __attribute__((ext_vector_type(4))) float f32x4;

__device__ __forceinline__ unsigned short f2b(float f) {
    union { float f; unsigned u; } v; v.f = f;
    unsigned r = (v.u + 0x7FFFu + ((v.u >> 16) & 1u)) >> 16;
    return (unsigned short)r;
}
__device__ __forceinline__ float b2f(unsigned short h) {
    union { unsigned u; float f; } v; v.u = ((unsigned)h) << 16;
    return v.f;
}

// async global->LDS 16B copy (dest: wave base + lane*16, lane-consecutive)
__device__ __forceinline__ void gl_lds16(const void* g, void* l) {
    __builtin_amdgcn_global_load_lds(
        (const __attribute__((address_space(1))) void*)g,
        (__attribute__((address_space(3))) void*)l, 16, 0, 0);
}

// ---------------------------------------------------------------------------
// K0: build AB2[g][208][512] bf16:
//   rows 0..127  = W1[g*128+d]          (xe part)
//   rows 128..191= V_g[k] = Wc[k].W1_g  (assignment part)
//   row 192      = W2W1[g]              (attention logit row)
//   rows 193..207= 0                    (pad)
// grid 1088: bid<1024 -> W1 convert + V; bid>=1024 -> W2W1 row + zero pad.
__global__ __launch_bounds__(256) void k0_prep(const float* __restrict__ W1,
                                               const float* __restrict__ Wc,
                                               const float* __restrict__ W2,
                                               unsigned short* __restrict__ AB2) {
    int bid = blockIdx.x;
    int t = threadIdx.x;
    if (bid < 1024) {
        // W1 -> bf16 into per-group rows (2 elems/thread, same row)
        int i0 = bid * 512 + t;
        {
            int e = i0 >> 9, c = i0 & 511;
            int g = e >> 7, d = e & 127;
            AB2[g * AB2_GS + d * 512 + c]       = f2b(W1[i0]);
            AB2[g * AB2_GS + d * 512 + c + 256] = f2b(W1[i0 + 256]);
        }
        // V rows
        int ch = bid & 1, k = (bid >> 1) & 63, g = bid >> 7;
        int c = ch * 256 + t;
        float acc = 0.f;
        #pragma unroll 8
        for (int d = 0; d < 128; ++d)
            acc += Wc[k * 128 + d] * W1[(g * 128 + d) * C_ + c];
        AB2[g * AB2_GS + (128 + k) * 512 + c] = f2b(acc);
    } else {
        int b2 = bid - 1024;                 // 0..63
        // W2W1 row: 4096 outputs, 4 lanes each
        int out = b2 * 64 + (t >> 2);
        int eq = t & 3;
        int g = out >> 9, c = out & 511;
        float acc = 0.f;
        int e0 = eq * 256;
        #pragma unroll 8
        for (int e = e0; e < e0 + 256; ++e)
            acc += W2[g * E_ + e] * W1[e * C_ + c];
        acc += __shfl_xor(acc, 1);
        acc += __shfl_xor(acc, 2);
        if (eq == 0) AB2[g * AB2_GS + 192 * 512 + c] = f2b(acc);
        // zero pad rows 193..207 (8 groups x 15 rows x 512 = 61440 shorts)
        int thr = b2 * 256 + t;
        int j0 = thr * 4;
        if (j0 < 61440) {
            int gg = j0 / 7680, rr = (j0 >> 9) % 15, cc = j0 & 511;
            unsigned short* p = &AB2[gg * AB2_GS + (193 + rr) * 512 + cc];
            p[0] = 0; p[1] = 0; p[2] = 0; p[3] = 0;
        }
    }
}

// ---------------------------------------------------------------------------
// K1: per-pixel L2 norm over C, write x_hat transposed: xhat_t [N][P][C] bf16
__global__ __launch_bounds__(256) void k1_norm_transpose(const float* __restrict__ x,
                                                         unsigned short* __restrict__ xhat_t) {
    __shared__ short xc[128 * 256];
    __shared__ float red[256];
    __shared__ float rn[64];
    int n = blockIdx.y;
    int p0 = blockIdx.x * 64;
    int t = threadIdx.x;
    int ps = t & 63, cs = t >> 6;

    float ss = 0.f;
    for (int i = 0; i < 128; ++i) {
        float v = x[((size_t)(n * C_ + cs * 128 + i)) * P_ + p0 + ps];
        ss += v * v;
        xc[i * 256 + t] = (short)f2b(v);
    }
    red[t] = ss;
    __syncthreads();
    if (t < 64) {
        float s = red[t] + red[64 + t] + red[128 + t] + red[192 + t];
        rn[t] = 1.0f / fmaxf(sqrtf(s), 1e-12f);
    }
    __syncthreads();

    float r = rn[ps];
    size_t base = ((size_t)(n * P_ + p0 + ps)) * C_ + cs * 128;
    #pragma unroll
    for (int jj = 0; jj < 16; ++jj) {
        bf16x8 o;
        #pragma unroll
        for (int j = 0; j < 8; ++j)
            o[j] = (short)f2b(b2f((unsigned short)xc[(jj * 8 + j) * 256 + t]) * r);
        *(bf16x8*)&xhat_t[base + jj * 8] = o;
    }
}

// ---------------------------------------------------------------------------
// KF: fused GEMM(M=208) + softmax + gate + aggregation per (n, g, pt).
// grid (64, 32): g = bx&7, pt = bx>>3 (128-px tile), n = by. 4 waves.
// Wave split: wc = p-half (64), wr -> m-tiles tt = 2j+wr (7 or 6 of 13).
__global__ __launch_bounds__(256) void kf_fused(const unsigned short* __restrict__ AB2,
                                                const unsigned short* __restrict__ xhat_t,
                                                float* __restrict__ agg_part,
                                                float* __restrict__ wsum_part) {
    __shared__ __align__(16) char smem[52736];
    short* alds = (short*)smem;                 // [208][72] staging (29952 B)
    short* blds = (short*)(smem + 29952);       // [128][72] staging (18432 B)
    short* xg   = (short*)smem;                 // [128][136] post: xe tile (34816 B)
    short* sw   = (short*)(smem + 34816);       // [64][136]  post: S then w (17408 B)
    float* attl = (float*)(smem + 52224);       // [128] gate

    int g = blockIdx.x & 7, pt = blockIdx.x >> 3, n = blockIdx.y;
    int t = threadIdx.x;
    int w = t >> 6, l = t & 63, q = l >> 4, l15 = l & 15;
    int wr = w >> 1, wc = w & 1;

    const unsigned short* Ag = AB2 + g * AB2_GS;
    const unsigned short* Bg = xhat_t + ((size_t)(n * P_ + pt * 128)) * C_;

    f32x4 acc[7][4];
    #pragma unroll
    for (int j = 0; j < 7; ++j)
        #pragma unroll
        for (int ni = 0; ni < 4; ++ni)
            acc[j][ni] = (f32x4){0.f, 0.f, 0.f, 0.f};

    for (int ks = 0; ks < 8; ++ks) {
        int k0 = ks * 64;
        // A tile: 208 rows x 9 chunks (8 data + 1 pad) = 1872 chunks
        #pragma unroll
        for (int i = 0; i < 7; ++i) {
            int ch = i * 256 + t;
            int row = ch / 9, col = (ch % 9) * 8;
            gl_lds16(&Ag[row * 512 + k0 + col], &alds[ch * 8]);
        }
        if (t < 80) {
            int ch = 1792 + t;
            int row = ch / 9, col = (ch % 9) * 8;
            gl_lds16(&Ag[row * 512 + k0 + col], &alds[ch * 8]);
        }
        // B tile: 128 rows x 9 chunks = 1152 chunks
        #pragma unroll
        for (int i = 0; i < 4; ++i) {
            int ch = i * 256 + t;
            int row = ch / 9, col = (ch % 9) * 8;
            gl_lds16(&Bg[row * 512 + k0 + col], &blds[ch * 8]);
        }
        if (t < 128) {
            int ch = 1024 + t;
            int row = ch / 9, col = (ch % 9) * 8;
            gl_lds16(&Bg[row * 512 + k0 + col], &blds[ch * 8]);
        }
        __syncthreads();

        #pragma unroll
        for (int kk = 0; kk < 2; ++kk) {
            bf16x8 bf[4];
            #pragma unroll
            for (int ni = 0; ni < 4; ++ni)
                bf[ni] = *(const bf16x8*)&blds[(wc * 64 + ni * 16 + l15) * 72 + kk * 32 + q * 8];
            #pragma unroll
            for (int j = 0; j < 7; ++j) {
                if (j < 6 || wr == 0) {            // wave-uniform guard (13 tiles)
                    int tt = 2 * j + wr;
                    bf16x8 af = *(const bf16x8*)&alds[(tt * 16 + l15) * 72 + kk * 32 + q * 8];
                    #pragma unroll
                    for (int ni = 0; ni < 4; ++ni)
                        acc[j][ni] = __builtin_amdgcn_mfma_f32_16x16x32_bf16(af, bf[ni], acc[j][ni], 0, 0, 0);
                }
            }
        }
        __syncthreads();
    }

    // ---- scatter results to LDS: xe tiles -> xg, S tiles -> sw, att row ----
    #pragma unroll
    for (int j = 0; j < 7; ++j) {
        if (j < 6 || wr == 0) {
            int tt = 2 * j + wr;
            if (tt < 8) {                                    // xe rows (d = tt*16..)
                #pragma unroll
                for (int ni = 0; ni < 4; ++ni)
                    #pragma unroll
                    for (int r = 0; r < 4; ++r)
                        xg[(tt * 16 + q * 4 + r) * 136 + wc * 64 + ni * 16 + l15] =
                            (short)f2b(acc[j][ni][r]);
            } else if (tt < 12) {                            // S rows (k = (tt-8)*16..)
                #pragma unroll
                for (int ni = 0; ni < 4; ++ni)
                    #pragma unroll
                    for (int r = 0; r < 4; ++r)
                        sw[((tt - 8) * 16 + q * 4 + r) * 136 + wc * 64 + ni * 16 + l15] =
                            (short)f2b(acc[j][ni][r]);
            } else {                                         // tt == 12: att logit row
                if (q == 0) {
                    #pragma unroll
                    for (int ni = 0; ni < 4; ++ni)
                        attl[wc * 64 + ni * 16 + l15] =
                            1.0f / (1.0f + __expf(-acc[j][ni][0]));
                }
            }
        }
    }
    __syncthreads();

    // ---- per-pixel softmax over 64 k + gate (threads 0..127), in-place ----
    if (t < 128) {
        float m = -1e30f;
        #pragma unroll 8
        for (int k = 0; k < 64; ++k)
            m = fmaxf(m, b2f((unsigned short)sw[k * 136 + t]));
        float s = 0.f;
        #pragma unroll 8
        for (int k = 0; k < 64; ++k)
            s += __expf(b2f((unsigned short)sw[k * 136 + t]) - m);
        float scale = attl[t] / s;
        #pragma unroll 8
        for (int k = 0; k < 64; ++k)
            sw[k * 136 + t] =
                (short)f2b(__expf(b2f((unsigned short)sw[k * 136 + t]) - m) * scale);
    }
    __syncthreads();

    // ---- agg MFMA: A = w [64k x 128p], B = xg [128d x 128p] (contract p) ----
    const short ONE = (short)0x3F80;
    bf16x8 ones = {ONE, ONE, ONE, ONE, ONE, ONE, ONE, ONE};
    f32x4 acc_a[4][2];
    #pragma unroll
    for (int mi = 0; mi < 4; ++mi)
        #pragma unroll
        for (int ni = 0; ni < 2; ++ni)
            acc_a[mi][ni] = (f32x4){0.f, 0.f, 0.f, 0.f};
    f32x4 acc_w[4];
    #pragma unroll
    for (int mi = 0; mi < 4; ++mi) acc_w[mi] = (f32x4){0.f, 0.f, 0.f, 0.f};

    #pragma unroll
    for (int pk = 0; pk < 4; ++pk) {
        bf16x8 a2[4], b2v[2];
        #pragma unroll
        for (int mi = 0; mi < 4; ++mi)
            a2[mi] = *(const bf16x8*)&sw[(mi * 16 + l15) * 136 + pk * 32 + q * 8];
        #pragma unroll
        for (int ni = 0; ni < 2; ++ni)
            b2v[ni] = *(const bf16x8*)&xg[(w * 32 + ni * 16 + l15) * 136 + pk * 32 + q * 8];
        #pragma unroll
        for (int mi = 0; mi < 4; ++mi) {
            #pragma unroll
            for (int ni = 0; ni < 2; ++ni)
                acc_a[mi][ni] = __builtin_amdgcn_mfma_f32_16x16x32_bf16(a2[mi], b2v[ni], acc_a[mi][ni], 0, 0, 0);
            acc_w[mi] = __builtin_amdgcn_mfma_f32_16x16x32_bf16(a2[mi], ones, acc_w[mi], 0, 0, 0);
        }
    }

    // ---- epilogue: disjoint partials [n][g][pt][k][d] ----
    size_t base = ((size_t)((n * 8 + g) * 8 + pt)) * 64;
    #pragma unroll
    for (int mi = 0; mi < 4; ++mi)
        #pragma unroll
        for (int ni = 0; ni < 2; ++ni)
            #pragma unroll
            for (int r = 0; r < 4; ++r) {
                int k = mi * 16 + q * 4 + r;
                int d = w * 32 + ni * 16 + l15;
                agg_part[(base + k) * 128 + d] = acc_a[mi][ni][r];
            }
    if (w == 0 && l15 == 0) {      // acc_w identical across waves/cols
        #pragma unroll
        for (int mi = 0; mi < 4; ++mi)
            #pragma unroll
            for (int r = 0; r < 4; ++r)
                wsum_part[base + mi * 16 + q * 4 + r] = acc_w[mi][r];
    }
}

// ---------------------------------------------------------------------------
// k4c: wsum[n][k] = sum over (g, pt)
__global__ __launch_bounds__(256) void k4c_wsum(const float* __restrict__ wsum_part,
                                                float* __restrict__ wsum) {
    int idx = blockIdx.x * 256 + threadIdx.x;   // grid 8 -> 2048
    int n = idx >> 6, k = idx & 63;
    float s = 0.f;
    #pragma unroll
    for (int g = 0; g < 8; ++g)
        #pragma unroll
        for (int pt = 0; pt < 8; ++pt)
            s += wsum_part[((size_t)((n * 8 + g) * 8 + pt)) * 64 + k];
    wsum[idx] = s;
}

// ---------------------------------------------------------------------------
// K5: vlad[n][k][d] = sum_{g,pt} agg_part - wsum[n][k] * centroids[k][d]
__global__ __launch_bounds__(256) void k5_final(const float* __restrict__ agg_part,
                                                const float* __restrict__ wsum,
                                                const float* __restrict__ centroids,
                                                float* __restrict__ out) {
    int idx = blockIdx.x * 256 + threadIdx.x;   // grid 1024 -> 262144
    int d = idx & 127;
    int k = (idx >> 7) & 63;
    int n = idx >> 13;
    float ag = 0.f;
    #pragma unroll
    for (int g = 0; g < 8; ++g)
        #pragma unroll
        for (int pt = 0; pt < 8; ++pt)
            ag += agg_part[(((size_t)((n * 8 + g) * 8 + pt)) * 64 + k) * 128 + d];
    out[idx] = ag - wsum[n * 64 + k] * centroids[k * 128 + d];
}

// ---------------------------------------------------------------------------
extern "C" void kernel_launch(void* const* d_in, const int* in_sizes, int n_in,
                              void* d_out, int out_size, void* d_ws, size_t ws_size,
                              hipStream_t stream) {
    const float* x         = (const float*)d_in[0];
    const float* W1        = (const float*)d_in[1];
    const float* W2        = (const float*)d_in[2];
    const float* Wc        = (const float*)d_in[3];
    const float* centroids = (const float*)d_in[4];
    float* out = (float*)d_out;

    // Workspace layout (total 102,899,840 B << proven 138.9 MB):
    //   AB2      [8][208][512] bf16  1,703,936 B @ 0  (+128 B DMA-pad slack)
    //   xhat_t   [N][P][C]     bf16 33,554,432 B @ 1,704,064
    //   agg_part [N][G][8][K][D] f32 67,108,864 B @ 35,258,496
    //   wsum_part[N][G][8][K]  f32     524,288 B @ 102,367,360
    //   wsum     [N][K]        f32       8,192 B @ 102,891,648
    char* ws = (char*)d_ws;
    unsigned short* AB2      = (unsigned short*)(ws + 0);
    unsigned short* xhat_t   = (unsigned short*)(ws + 1704064);
    float*          agg_part = (float*)(ws + 35258496);
    float*          wsum_part= (float*)(ws + 102367360);
    float*          wsum     = (float*)(ws + 102891648);

    hipLaunchKernelGGL(k0_prep,        dim3(1088), dim3(256), 0, stream, W1, Wc, W2, AB2);
    hipLaunchKernelGGL(k1_norm_transpose, dim3(16, 32), dim3(256), 0, stream, x, xhat_t);
    hipLaunchKernelGGL(kf_fused,       dim3(64, 32), dim3(256), 0, stream,
                       AB2, xhat_t, agg_part, wsum_part);
    hipLaunchKernelGGL(k4c_wsum,       dim3(8), dim3(256), 0, stream, wsum_part, wsum);
    hipLaunchKernelGGL(k5_final,       dim3(1024), dim3(256), 0, stream,
                       agg_part, wsum, centroids, out);
}

// Round 10
// 287.675 us; speedup vs baseline: 1.2960x; 1.2960x over previous
//
#include <hip/hip_runtime.h>

// ---------------------------------------------------------------------------
// TransVLAD fused pipeline for MI355X (gfx950)
// Shapes: N=32, C=512, H=W=32 (P=1024), E=1024, G=8, D=128, K=64
// out: [N, K*D] fp32 (262144)
//
// R10: revert to R6 pipeline (best, 253.6us) + fix the diagnosed 16-way LDS
// bank conflicts: GEMM fragment reads had row strides = k*128B (bank(row)
// const across the 16 l15 lanes). Pad k2 As/Bs and k4 As2/Bs2 rows to
// 72 shorts (144B = 4-bank shift/row -> free 2-way). Staging uses kf-style
// 9-chunk rows (8 data + 1 harmless overrun chunk) to satisfy
// global_load_lds lane-contiguity.
// ---------------------------------------------------------------------------

#define N_  32
#define C_  512
#define P_  1024
#define E_  1024
#define G_  8
#define D_  128
#define K_  64

typedef __attribute__((ext_vector_type(8))) short bf16x8;
typedef __attribute__((ext_vector_type(4))) float f32x4;

__device__ __forceinline__ unsigned short f2b(float f) {
    union { float f; unsigned u; } v; v.f = f;
    unsigned r = (v.u + 0x7FFFu + ((v.u >> 16) & 1u)) >> 16;
    return (unsigned short)r;
}
__device__ __forceinline__ float b2f(unsigned short h) {
    union { unsigned u; float f; } v; v.u = ((unsigned)h) << 16;
    return v.f;
}

// async global->LDS 16B copy: LDS dest must be wave-uniform base + lane*16
__device__ __forceinline__ void gl_lds16(const void* g, void* l) {
    __builtin_amdgcn_global_load_lds(
        (const __attribute__((address_space(1))) void*)g,
        (__attribute__((address_space(3))) void*)l, 16, 0, 0);
}

// ---------------------------------------------------------------------------
// K0: convert W1 -> bf16 AND build V[g][k][c] = sum_d Wc[k][d]*W1[g*128+d][c]
__global__ __launch_bounds__(256) void k0_prep(const float* __restrict__ W1,
                                               const float* __restrict__ Wc,
                                               unsigned short* __restrict__ W1b,
                                               unsigned short* __restrict__ Vb) {
    int bid = blockIdx.x;
    int t = threadIdx.x;
    int i0 = bid * 512 + t;
    W1b[i0]       = f2b(W1[i0]);
    W1b[i0 + 256] = f2b(W1[i0 + 256]);
    int ch = bid & 1, k = (bid >> 1) & 63, g = bid >> 7;
    int c = ch * 256 + t;
    float acc = 0.f;
    #pragma unroll 8
    for (int d = 0; d < 128; ++d)
        acc += Wc[k * 128 + d] * W1[(g * 128 + d) * C_ + c];
    Vb[(g * 64 + k) * C_ + c] = f2b(acc);
}

// ---------------------------------------------------------------------------
// K1: per-pixel L2 norm over C, write x_hat transposed: xhat_t [N][P][C] bf16
__global__ __launch_bounds__(256) void k1_norm_transpose(const float* __restrict__ x,
                                                         unsigned short* __restrict__ xhat_t) {
    __shared__ short xc[128 * 256];
    __shared__ float red[256];
    __shared__ float rn[64];
    int n = blockIdx.y;
    int p0 = blockIdx.x * 64;
    int t = threadIdx.x;
    int ps = t & 63, cs = t >> 6;

    float ss = 0.f;
    for (int i = 0; i < 128; ++i) {
        float v = x[((size_t)(n * C_ + cs * 128 + i)) * P_ + p0 + ps];
        ss += v * v;
        xc[i * 256 + t] = (short)f2b(v);
    }
    red[t] = ss;
    __syncthreads();
    if (t < 64) {
        float s = red[t] + red[64 + t] + red[128 + t] + red[192 + t];
        rn[t] = 1.0f / fmaxf(sqrtf(s), 1e-12f);
    }
    __syncthreads();

    float r = rn[ps];
    size_t base = ((size_t)(n * P_ + p0 + ps)) * C_ + cs * 128;
    #pragma unroll
    for (int jj = 0; jj < 16; ++jj) {
        bf16x8 o;
        #pragma unroll
        for (int j = 0; j < 8; ++j)
            o[j] = (short)f2b(b2f((unsigned short)xc[(jj * 8 + j) * 256 + t]) * r);
        *(bf16x8*)&xhat_t[base + jj * 8] = o;
    }
}

// ---------------------------------------------------------------------------
// K2: xe[n][e][p] = sum_c W1b[e][c] * xhat_t[n][p][c]  (bf16 MFMA, BK=64)
// grid (64, 32). LDS rows padded to 72 shorts -> conflict-free fragment reads.
__global__ __launch_bounds__(256) void k2_gemm_xe(const unsigned short* __restrict__ W1b,
                                                  const unsigned short* __restrict__ xhat_t,
                                                  unsigned short* __restrict__ xe) {
    __shared__ __align__(16) short As[128 * 72];
    __shared__ __align__(16) short Bs[128 * 72];
    int n = blockIdx.y;
    int e0 = (blockIdx.x >> 3) * 128;
    int p0 = (blockIdx.x & 7) * 128;
    int t = threadIdx.x;
    int w = t >> 6, l = t & 63, q = l >> 4, l15 = l & 15;
    int wr = w >> 1, wc = w & 1;

    f32x4 acc[4][4];
    #pragma unroll
    for (int mi = 0; mi < 4; ++mi)
        #pragma unroll
        for (int ni = 0; ni < 4; ++ni)
            acc[mi][ni] = (f32x4){0.f, 0.f, 0.f, 0.f};

    for (int ks = 0; ks < 8; ++ks) {
        int k0 = ks * 64;
        // A tile: 128 rows x 9 chunks (8 data + 1 overrun pad) = 1152 chunks
        #pragma unroll
        for (int i = 0; i < 4; ++i) {
            int ch = i * 256 + t;
            int row = ch / 9, col = (ch % 9) * 8;
            gl_lds16(&W1b[(e0 + row) * C_ + k0 + col], &As[ch * 8]);
        }
        if (t < 128) {
            int ch = 1024 + t;
            int row = ch / 9, col = (ch % 9) * 8;
            gl_lds16(&W1b[(e0 + row) * C_ + k0 + col], &As[ch * 8]);
        }
        // B tile: same shape
        #pragma unroll
        for (int i = 0; i < 4; ++i) {
            int ch = i * 256 + t;
            int row = ch / 9, col = (ch % 9) * 8;
            gl_lds16(&xhat_t[((size_t)(n * P_ + p0 + row)) * C_ + k0 + col], &Bs[ch * 8]);
        }
        if (t < 128) {
            int ch = 1024 + t;
            int row = ch / 9, col = (ch % 9) * 8;
            gl_lds16(&xhat_t[((size_t)(n * P_ + p0 + row)) * C_ + k0 + col], &Bs[ch * 8]);
        }
        __syncthreads();

        #pragma unroll
        for (int kk = 0; kk < 2; ++kk) {
            bf16x8 af[4], bf[4];
            #pragma unroll
            for (int mi = 0; mi < 4; ++mi)
                af[mi] = *(const bf16x8*)&As[(wr * 64 + mi * 16 + l15) * 72 + kk * 32 + q * 8];
            #pragma unroll
            for (int ni = 0; ni < 4; ++ni)
                bf[ni] = *(const bf16x8*)&Bs[(wc * 64 + ni * 16 + l15) * 72 + kk * 32 + q * 8];
            #pragma unroll
            for (int mi = 0; mi < 4; ++mi)
                #pragma unroll
                for (int ni = 0; ni < 4; ++ni)
                    acc[mi][ni] = __builtin_amdgcn_mfma_f32_16x16x32_bf16(af[mi], bf[ni], acc[mi][ni], 0, 0, 0);
        }
        __syncthreads();
    }

    #pragma unroll
    for (int mi = 0; mi < 4; ++mi) {
        #pragma unroll
        for (int ni = 0; ni < 4; ++ni) {
            #pragma unroll
            for (int r = 0; r < 4; ++r) {
                int e = e0 + wr * 64 + mi * 16 + q * 4 + r;
                int p = p0 + wc * 64 + ni * 16 + l15;
                xe[((size_t)(n * E_ + e)) * P_ + p] = f2b(acc[mi][ni][r]);
            }
        }
    }
}

// ---------------------------------------------------------------------------
// K3a: att partials over 64-wide e-chunks, 4 pixels/thread (ushort4/float4).
__global__ __launch_bounds__(256) void k3a_att_part(const unsigned short* __restrict__ xe,
                                                    const float* __restrict__ W2,
                                                    float* __restrict__ att_part) {
    int n = blockIdx.y;
    int ec = blockIdx.x;
    int t = threadIdx.x;
    int e0 = ec * 64;
    f32x4 acc[8];
    #pragma unroll
    for (int g = 0; g < 8; ++g) acc[g] = (f32x4){0.f, 0.f, 0.f, 0.f};
    #pragma unroll 4
    for (int i = 0; i < 64; ++i) {
        int e = e0 + i;
        ushort4 v4 = *(const ushort4*)&xe[((size_t)(n * E_ + e)) * P_ + t * 4];
        f32x4 vf = {b2f(v4.x), b2f(v4.y), b2f(v4.z), b2f(v4.w)};
        #pragma unroll
        for (int g = 0; g < 8; ++g)
            acc[g] += vf * W2[g * E_ + e];
    }
    #pragma unroll
    for (int g = 0; g < 8; ++g)
        *(f32x4*)&att_part[(((size_t)(n * 16 + ec)) * 8 + g) * P_ + t * 4] = acc[g];
}

// K3b: att_s[n][g][p] = sigmoid( sum_ec att_part[n][ec][g][p] )
__global__ __launch_bounds__(256) void k3b_att_reduce(const float* __restrict__ att_part,
                                                      float* __restrict__ att_s) {
    int idx = blockIdx.x * 256 + threadIdx.x;
    int p = idx & 1023;
    int g = (idx >> 10) & 7;
    int n = idx >> 13;
    float s = 0.f;
    #pragma unroll
    for (int ec = 0; ec < 16; ++ec)
        s += att_part[(((size_t)(n * 16 + ec)) * 8 + g) * P_ + p];
    att_s[idx] = 1.0f / (1.0f + __expf(-s));
}

// ---------------------------------------------------------------------------
// K4: fused assignment -> softmax -> gate -> aggregation per (n, g, ph)
// grid (16, 32). BK=64 S-phase, rows padded to 72 shorts (conflict-free).
// LDS: As2 9216 + Bs2 18432 + xglds 34816 + wlds 17408 = 79,872 B.
__global__ __launch_bounds__(256) void k4_assign_agg(const unsigned short* __restrict__ Vb,
                                                     const unsigned short* __restrict__ xhat_t,
                                                     const unsigned short* __restrict__ xe,
                                                     const float* __restrict__ att_s,
                                                     float* __restrict__ agg_part,
                                                     float* __restrict__ wsum_part) {
    __shared__ __align__(16) char smem[9216 + 18432 + 34816 + 17408];
    short* As2   = (short*)smem;                 // [64][72]
    short* Bs2   = (short*)(smem + 9216);        // [128][72]
    short* xglds = (short*)(smem + 27648);       // [128][136]
    short* wlds  = (short*)(smem + 62464);       // [64][136]

    int g = blockIdx.x & 7, ph = blockIdx.x >> 3, n = blockIdx.y;
    int t = threadIdx.x;
    int w = t >> 6, l = t & 63, q = l >> 4, l15 = l & 15;

    f32x4 acc_a[4][2];
    #pragma unroll
    for (int mi = 0; mi < 4; ++mi)
        #pragma unroll
        for (int ni = 0; ni < 2; ++ni)
            acc_a[mi][ni] = (f32x4){0.f, 0.f, 0.f, 0.f};
    float wsp[16];
    #pragma unroll
    for (int j = 0; j < 16; ++j) wsp[j] = 0.f;

    for (int cc = 0; cc < 4; ++cc) {
        int p0c = ph * 512 + cc * 128;

        // ---- issue xg staging FIRST (drains behind S barriers) ----
        #pragma unroll
        for (int i = 0; i < 8; ++i) {
            int ch = i * 256 + t;
            int row = ch / 17, col = (ch % 17) * 8;
            gl_lds16(&xe[((size_t)(n * E_ + g * 128 + row)) * P_ + p0c + col], &xglds[ch * 8]);
        }
        if (t < 128) {
            int ch = 2048 + t;
            int row = ch / 17, col = (ch % 17) * 8;
            gl_lds16(&xe[((size_t)(n * E_ + g * 128 + row)) * P_ + p0c + col], &xglds[ch * 8]);
        }

        // ---- Phase S: S = Vb[g] (64xC) * xhat^T (Cx128), BK=64, padded ----
        f32x4 acc_s[4][2];
        #pragma unroll
        for (int mi = 0; mi < 4; ++mi)
            #pragma unroll
            for (int ni = 0; ni < 2; ++ni)
                acc_s[mi][ni] = (f32x4){0.f, 0.f, 0.f, 0.f};

        for (int ks = 0; ks < 8; ++ks) {
            int k0 = ks * 64;
            // As2: 64 rows x 9 chunks = 576 chunks
            #pragma unroll
            for (int i = 0; i < 2; ++i) {
                int ch = i * 256 + t;
                int row = ch / 9, col = (ch % 9) * 8;
                gl_lds16(&Vb[(g * 64 + row) * C_ + k0 + col], &As2[ch * 8]);
            }
            if (t < 64) {
                int ch = 512 + t;
                int row = ch / 9, col = (ch % 9) * 8;
                gl_lds16(&Vb[(g * 64 + row) * C_ + k0 + col], &As2[ch * 8]);
            }
            // Bs2: 128 rows x 9 chunks = 1152 chunks
            #pragma unroll
            for (int i = 0; i < 4; ++i) {
                int ch = i * 256 + t;
                int row = ch / 9, col = (ch % 9) * 8;
                gl_lds16(&xhat_t[((size_t)(n * P_ + p0c + row)) * C_ + k0 + col], &Bs2[ch * 8]);
            }
            if (t < 128) {
                int ch = 1024 + t;
                int row = ch / 9, col = (ch % 9) * 8;
                gl_lds16(&xhat_t[((size_t)(n * P_ + p0c + row)) * C_ + k0 + col], &Bs2[ch * 8]);
            }
            __syncthreads();
            #pragma unroll
            for (int kk = 0; kk < 2; ++kk) {
                bf16x8 af[4], bf2[2];
                #pragma unroll
                for (int mi = 0; mi < 4; ++mi)
                    af[mi] = *(const bf16x8*)&As2[(mi * 16 + l15) * 72 + kk * 32 + q * 8];
                #pragma unroll
                for (int ni = 0; ni < 2; ++ni)
                    bf2[ni] = *(const bf16x8*)&Bs2[(w * 32 + ni * 16 + l15) * 72 + kk * 32 + q * 8];
                #pragma unroll
                for (int mi = 0; mi < 4; ++mi)
                    #pragma unroll
                    for (int ni = 0; ni < 2; ++ni)
                        acc_s[mi][ni] = __builtin_amdgcn_mfma_f32_16x16x32_bf16(af[mi], bf2[ni], acc_s[mi][ni], 0, 0, 0);
            }
            __syncthreads();
        }

        // ---- softmax over k + gate (writes wlds only) ----
        #pragma unroll
        for (int ni = 0; ni < 2; ++ni) {
            float m = -1e30f;
            #pragma unroll
            for (int mi = 0; mi < 4; ++mi)
                #pragma unroll
                for (int r = 0; r < 4; ++r)
                    m = fmaxf(m, acc_s[mi][ni][r]);
            m = fmaxf(m, __shfl_xor(m, 16));
            m = fmaxf(m, __shfl_xor(m, 32));
            float s = 0.f;
            #pragma unroll
            for (int mi = 0; mi < 4; ++mi)
                #pragma unroll
                for (int r = 0; r < 4; ++r) {
                    float e = __expf(acc_s[mi][ni][r] - m);
                    acc_s[mi][ni][r] = e;
                    s += e;
                }
            s += __shfl_xor(s, 16);
            s += __shfl_xor(s, 32);

            int pcol = p0c + w * 32 + ni * 16 + l15;
            float av = att_s[(((size_t)(n * G_ + g)) * P_) + pcol];  // pre-sigmoided
            float scale = av / s;

            #pragma unroll
            for (int mi = 0; mi < 4; ++mi)
                #pragma unroll
                for (int r = 0; r < 4; ++r) {
                    float wv = acc_s[mi][ni][r] * scale;
                    wsp[mi * 4 + r] += wv;
                    wlds[(mi * 16 + q * 4 + r) * 136 + (w * 32 + ni * 16 + l15)] = (short)f2b(wv);
                }
        }
        __syncthreads();   // wlds visible; xglds long since drained

        // ---- agg MFMA: A = w [64k x 128p], B = xg [128d x 128p] (NT) ----
        #pragma unroll
        for (int pk = 0; pk < 4; ++pk) {
            bf16x8 a2[4], b2[2];
            #pragma unroll
            for (int mi = 0; mi < 4; ++mi)
                a2[mi] = *(const bf16x8*)&wlds[(mi * 16 + l15) * 136 + pk * 32 + q * 8];
            #pragma unroll
            for (int ni = 0; ni < 2; ++ni)
                b2[ni] = *(const bf16x8*)&xglds[(w * 32 + ni * 16 + l15) * 136 + pk * 32 + q * 8];
            #pragma unroll
            for (int mi = 0; mi < 4; ++mi)
                #pragma unroll
                for (int ni = 0; ni < 2; ++ni)
                    acc_a[mi][ni] = __builtin_amdgcn_mfma_f32_16x16x32_bf16(a2[mi], b2[ni], acc_a[mi][ni], 0, 0, 0);
        }
        __syncthreads();   // xglds/wlds reads done before next cc re-stages
    }

    // ---- epilogue: disjoint partials ----
    size_t base = (((size_t)(n * G_ + g)) * 2 + ph) * 64;
    #pragma unroll
    for (int mi = 0; mi < 4; ++mi)
        #pragma unroll
        for (int ni = 0; ni < 2; ++ni)
            #pragma unroll
            for (int r = 0; r < 4; ++r) {
                int k = mi * 16 + q * 4 + r;
                int d = w * 32 + ni * 16 + l15;
                agg_part[(base + k) * 128 + d] = acc_a[mi][ni][r];
            }

    #pragma unroll
    for (int j = 0; j < 16; ++j) {
        float v = wsp[j];
        v += __shfl_xor(v, 1);
        v += __shfl_xor(v, 2);
        v += __shfl_xor(v, 4);
        v += __shfl_xor(v, 8);
        if (l15 == 0) {
            int k = (j >> 2) * 16 + q * 4 + (j & 3);
            wsum_part[((((size_t)(n * G_ + g)) * 2 + ph) * 4 + w) * 64 + k] = v;
        }
    }
}

// ---------------------------------------------------------------------------
// K5: vlad[n][k][d] = sum_{g,ph} agg_part - (sum) * centroids
__global__ __launch_bounds__(256) void k5_final(const float* __restrict__ agg_part,
                                                const float* __restrict__ wsum_part,
                                                const float* __restrict__ centroids,
                                                float* __restrict__ out) {
    int idx = blockIdx.x * 256 + threadIdx.x;
    int d = idx & 127;
    int k = (idx >> 7) & 63;
    int n = idx >> 13;
    float ws = 0.f;
    #pragma unroll
    for (int g = 0; g < 8; ++g)
        #pragma unroll
        for (int ph = 0; ph < 2; ++ph)
            #pragma unroll
            for (int w2 = 0; w2 < 4; ++w2)
                ws += wsum_part[((((size_t)(n * G_ + g)) * 2 + ph) * 4 + w2) * 64 + k];
    float agg = 0.f;
    #pragma unroll
    for (int g = 0; g < 8; ++g)
        #pragma unroll
        for (int ph = 0; ph < 2; ++ph)
            agg += agg_part[(((((size_t)(n * G_ + g)) * 2 + ph) * 64) + k) * 128 + d];
    out[idx] = agg - ws * centroids[k * 128 + d];
}

// ---------------------------------------------------------------------------
extern "C" void kernel_launch(void* const* d_in, const int* in_sizes, int n_in,
                              void* d_out, int out_size, void* d_ws, size_t ws_size,
                              hipStream_t stream) {
    const float* x         = (const float*)d_in[0];
    const float* W1        = (const float*)d_in[1];
    const float* W2        = (const float*)d_in[2];
    const float* Wc        = (const float*)d_in[3];
    const float* centroids = (const float*)d_in[4];
    float* out = (float*)d_out;

    // Workspace layout (total 120,324,096 B == proven footprint):
    //   W1b      [E*C]        bf16   1,048,576 B @ 0
    //   Vb       [G*K*C]      bf16     524,288 B @ 1,048,576
    //   xhat_t   [N*P*C]      bf16  33,554,432 B @ 1,572,864
    //   xe       [N*E*P]      bf16  67,108,864 B @ 35,127,296
    //   att_s    [N*G*P]      f32    1,048,576 B @ 102,236,160
    //   att_part [N*16*G*P]   f32   16,777,216 B @ 103,284,736 (dead after k3b;
    //   agg_part [N*G*2*K*D]  f32   16,777,216 B @ 103,284,736  aliases att_part)
    //   wsum_part[N*G*2*4*K]  f32      262,144 B @ 120,061,952
    char* ws = (char*)d_ws;
    unsigned short* W1b      = (unsigned short*)(ws + 0);
    unsigned short* Vb       = (unsigned short*)(ws + 1048576);
    unsigned short* xhat_t   = (unsigned short*)(ws + 1572864);
    unsigned short* xe       = (unsigned short*)(ws + 35127296);
    float*          att_s    = (float*)(ws + 102236160);
    float*          att_part = (float*)(ws + 103284736);
    float*          agg_part = (float*)(ws + 103284736);   // alias: att_part dead before K4
    float*          wsum_part= (float*)(ws + 120061952);

    hipLaunchKernelGGL(k0_prep,        dim3(1024), dim3(256), 0, stream, W1, Wc, W1b, Vb);
    hipLaunchKernelGGL(k1_norm_transpose, dim3(16, 32), dim3(256), 0, stream, x, xhat_t);
    hipLaunchKernelGGL(k2_gemm_xe,     dim3(64, 32), dim3(256), 0, stream, W1b, xhat_t, xe);
    hipLaunchKernelGGL(k3a_att_part,   dim3(16, 32), dim3(256), 0, stream, xe, W2, att_part);
    hipLaunchKernelGGL(k3b_att_reduce, dim3(1024), dim3(256), 0, stream, att_part, att_s);
    hipLaunchKernelGGL(k4_assign_agg,  dim3(16, 32), dim3(256), 0, stream, Vb, xhat_t, xe,
                       att_s, agg_part, wsum_part);
    hipLaunchKernelGGL(k5_final,       dim3(1024), dim3(256), 0, stream,
                       agg_part, wsum_part, centroids, out);
}